// Round 5
// baseline (899.907 us; speedup 1.0000x reference)
//
#include <hip/hip_runtime.h>
#include <math.h>

typedef unsigned int u32;

#define BB 64
#define NN 20000
#define LL 336
#define PP 96
#define CC 16
#define DD 64
#define KC 80
#define TM 20
#define LC 5376     // L*C
#define NTAB 17
#define GH 128
#define CAP 2048    // threshold-bin candidate buffer

__constant__ int c_idmin[17] = {0,0,0,0,0,1,1,0,0,0,0,0,0,0,0,0,0};
__constant__ int c_idmax[17] = {2047,255,4095,23,6,12,53,3,1,1,15,7,2,2,2,2,1};

__device__ __forceinline__ float gelu(float x){ return 0.5f*x*(1.0f + erff(x*0.70710678118654752440f)); }
__device__ __forceinline__ float wred(float v){
  #pragma unroll
  for(int m=32;m>=1;m>>=1) v += __shfl_xor(v, m, 64);
  return v;
}
__device__ __forceinline__ u32 fkey(float f){
  u32 u = __float_as_uint(f);
  return (u & 0x80000000u) ? ~u : (u | 0x80000000u);
}

// ---------------- workspace layout (bytes) ----------------
#define OFF_Q     0u            // 4096 f32
#define OFF_QN    16384u        // 4096 f32
#define OFF_XN    32768u        // 64 f32
#define OFF_CIDX  33024u        // 64*80 i32
#define OFF_METC  53504u        // 64*80 f32
#define OFF_COMB  73984u        // 64*80 f32
#define OFF_SIM   106496u       // 64*20000 f32 = 5,120,000 B
#define OFF_HIST  5226496u      // 64*4096 u32 = 1,048,576 B
#define WS_NEED   6275072u
// ghist uint4 count: 64*4096 u32 = 262144 u32 = 262144/4 = 65536 uint4
#define GHIST_U4  65536

// =============== 1. context encoder -> q, qn, xnorm (+ zero ghist) ===============
__global__ __launch_bounds__(64) void k_ctx(
    const int* __restrict__ mids, const float* __restrict__ exo,
    const float* __restrict__ locs, const float* __restrict__ x,
    const float* __restrict__ emb,
    const float* __restrict__ cw1, const float* __restrict__ cb1,
    const float* __restrict__ cw2, const float* __restrict__ cb2,
    const float* __restrict__ ew1, const float* __restrict__ eb1,
    const float* __restrict__ ew2, const float* __restrict__ eb2,
    const float* __restrict__ lw1, const float* __restrict__ lb1,
    const float* __restrict__ lw2, const float* __restrict__ lb2,
    const float* __restrict__ lng, const float* __restrict__ lnb,
    float* __restrict__ q, float* __restrict__ qn, float* __restrict__ xn,
    u32* __restrict__ ghist)
{
  int b = blockIdx.x, j = threadIdx.x;
  __shared__ float s_cat[272];
  __shared__ float s_h[64];
  __shared__ float s_exo[8];
  __shared__ float s_loc[12];

  // zero the global per-b histogram: 65536 uint4 total, 4096 threads grid-wide
  if(ghist){
    uint4* g4 = (uint4*)ghist;
    int gid = b*64 + j;                       // 0..4095
    for(int e=gid; e<GHIST_U4; e+=4096) g4[e] = make_uint4(0u,0u,0u,0u);
  }

  for(int e=j; e<272; e+=64){
    int t=e>>4, c=e&15;
    int id = mids[b*NTAB + t];
    if(id < c_idmin[t]) id = c_idmin[t];
    if(id > c_idmax[t]) id = c_idmax[t];
    s_cat[e] = emb[((size_t)t*4096 + id)*16 + c];
  }
  if(j<8)  s_exo[j] = exo[b*8+j];
  if(j<12) s_loc[j] = locs[b*12+j];
  __syncthreads();

  // cat MLP: 272 -> 64 (gelu) -> 64
  float a = cb1[j];
  for(int i=0;i<272;i++) a += s_cat[i]*cw1[i*64+j];
  s_h[j] = gelu(a);
  __syncthreads();
  float cc = cb2[j];
  for(int k=0;k<64;k++) cc += s_h[k]*cw2[k*64+j];
  __syncthreads();

  // exo MLP: 8 -> 64 (gelu) -> 64
  a = eb1[j];
  for(int i=0;i<8;i++) a += s_exo[i]*ew1[i*64+j];
  s_h[j] = gelu(a);
  __syncthreads();
  float ec = eb2[j];
  for(int k=0;k<64;k++) ec += s_h[k]*ew2[k*64+j];
  cc += ec;
  __syncthreads();

  // loc MLP per period r: 4 -> 64 (gelu) -> 64
  float lr[3];
  for(int r=0;r<3;r++){
    a = lb1[j];
    for(int i=0;i<4;i++) a += s_loc[r*4+i]*lw1[i*64+j];
    s_h[j] = gelu(a);
    __syncthreads();
    float o = lb2[j];
    for(int k=0;k<64;k++) o += s_h[k]*lw2[k*64+j];
    lr[r] = o;
    __syncthreads();
  }

  // LayerNorm per period + mean over periods
  float g = lng[j], be = lnb[j];
  float qa = 0.f;
  for(int r=0;r<3;r++){
    float v = cc + lr[r];
    float mean = wred(v) * (1.0f/64.0f);
    float d = v - mean;
    float var = wred(d*d) * (1.0f/64.0f);
    qa += d / sqrtf(var + 1e-5f) * g + be;
  }
  float qv = qa * (1.0f/3.0f);
  q[b*64+j] = qv;
  float s2 = wred(qv*qv);
  qn[b*64+j] = qv / (sqrtf(s2) + 1e-12f);

  // ||x[b]|| over 5376 elements
  float xa = 0.f;
  for(int e=j; e<LC; e+=64){ float f = x[(size_t)b*LC+e]; xa += f*f; }
  xa = wred(xa);
  if(j==0) xn[b] = sqrtf(xa);
}

// shared sim routine (fallback path): noinline so both passes emit the SAME
// code instance -> bitwise-identical values in histogram and collect passes.
__device__ __attribute__((noinline)) float row_sim(const float* pr, const float* sq)
{
  const float4* p4 = (const float4*)pr;
  float dot=0.f, ns=0.f;
  #pragma unroll
  for(int i=0;i<16;i++){
    float4 u = p4[i];
    dot += u.x*sq[i*4+0] + u.y*sq[i*4+1] + u.z*sq[i*4+2] + u.w*sq[i*4+3];
    ns  += u.x*u.x + u.y*u.y + u.z*u.z + u.w*u.w;
  }
  return dot / (sqrtf(ns) + 1e-12f);
}

// =============== 2a. coarse sims + fused histogram ===============
// 313 blocks; each block owns a 64-n tile and computes sims for ALL 64 b.
// pool_context is read from HBM exactly once. Pool row held in registers;
// ns chain computed once per n (identical FP order to row_sim); per-b dot
// chain identical; division kept as division -> sims match fallback path.
// Histogram: per-b 4096-bin global hist via wave-aggregated atomics (ballot
// leader dedup) -> hot-bin contention is ~#waves, not #items.
__global__ __launch_bounds__(256) void k_sim(const float* __restrict__ pc,
    const float* __restrict__ qn, float* __restrict__ sim, u32* __restrict__ ghist)
{
  __shared__ float s_pc[64*68];   // row stride 68 f32: b128 reads conflict-free
  __shared__ float s_qn[64*64];   // all 64 query rows (broadcast reads)
  int n0 = blockIdx.x << 6;
  int tid = threadIdx.x;

  const float4* pc4 = (const float4*)pc;
  for(int e=tid; e<64*16; e+=256){
    int r = e>>4, c = e&15;
    float4 v;
    if(n0 + r < NN) v = pc4[(size_t)(n0+r)*16 + c];
    else            v = make_float4(0.f,0.f,0.f,0.f);
    *(float4*)&s_pc[r*68 + c*4] = v;
  }
  const float4* qn4 = (const float4*)qn;
  for(int e=tid; e<1024; e+=256) ((float4*)s_qn)[e] = qn4[e];
  __syncthreads();

  int w = tid>>6, ln = tid&63;
  int n = n0 + ln;
  bool valid = (n < NN);

  // hoist pool row into registers
  float4 pr[16];
  #pragma unroll
  for(int i=0;i<16;i++) pr[i] = *(const float4*)&s_pc[ln*68 + i*4];
  // ns chain, same order as row_sim
  float ns = 0.f;
  #pragma unroll
  for(int i=0;i<16;i++) ns += pr[i].x*pr[i].x + pr[i].y*pr[i].y + pr[i].z*pr[i].z + pr[i].w*pr[i].w;
  float denom = sqrtf(ns) + 1e-12f;

  unsigned long long vmask = __ballot(valid);
  for(int bi=w; bi<64; bi+=4){
    const float4* q4 = (const float4*)&s_qn[bi*64];
    float dot = 0.f;
    #pragma unroll
    for(int i=0;i<16;i++){
      float4 qv = q4[i];
      dot += pr[i].x*qv.x + pr[i].y*qv.y + pr[i].z*qv.z + pr[i].w*qv.w;
    }
    float v = dot / denom;
    if(valid) sim[(size_t)bi*NN + n] = v;

    // wave-aggregated histogram add
    u32 key = fkey(v)>>20;
    unsigned long long active = vmask;
    while(active){
      int leader = __ffsll((long long)active) - 1;
      u32 lk = __shfl(key, leader, 64);
      unsigned long long eq = __ballot(valid && key==lk);
      if(ln==leader) atomicAdd(&ghist[bi*4096+lk], (u32)__popcll(eq));
      active &= ~eq;
    }
  }
}

// =============== 2b. exact top-80 per batch row (hist precomputed) ===============
// Hierarchical radix select: threshold bin T from the precomputed histogram;
// collect pass; then sub-histogram (key bits 8..19) over the tie items in LDS
// -> T2; direct-emit sub>T2; tiny serial residual. Selected SET identical.
__global__ __launch_bounds__(256) void k_sel(const float* __restrict__ sim,
    const u32* __restrict__ ghist, int* __restrict__ cidx_out, float* __restrict__ metc)
{
  __shared__ u32 hist[4096];
  __shared__ u32 cs[256];
  __shared__ float cval[CAP];
  __shared__ int  cidxs[CAP];
  __shared__ int s_T; __shared__ u32 s_above;
  __shared__ int s_T2; __shared__ u32 s_above2;
  __shared__ u32 s_na, s_nc, s_nb;
  __shared__ float swv[4]; __shared__ int swi[4];
  int b = blockIdx.x, tid = threadIdx.x;
  const float* srow = sim + (size_t)b*NN;
  const float4* srow4 = (const float4*)srow;   // NN = 20000 = 5000 float4

  // load per-b histogram computed by k_sim
  for(int e=tid;e<4096;e+=256) hist[e] = ghist[b*4096+e];
  if(tid==0){ s_na=0; s_nc=0; s_nb=0; }
  // defensive prefill: any slot a later pass fails to write stays a VALID index
  for(int e=tid;e<KC;e+=256){ cidx_out[b*KC+e]=0; metc[b*KC+e]=-1.0f; }
  __syncthreads();

  u32 c=0;
  #pragma unroll
  for(int i=0;i<16;i++) c += hist[tid*16+i];
  cs[tid]=c;
  __syncthreads();
  if(tid==0){
    u32 acc=0, above=0; int T=0;
    for(int ch=255; ch>=0; --ch){
      if(acc + cs[ch] >= (u32)KC){
        for(int bin=ch*16+15;; --bin){
          if(acc + hist[bin] >= (u32)KC){ T=bin; above=acc; break; }
          acc += hist[bin];
        }
        break;
      }
      acc += cs[ch];
    }
    s_T = T; s_above = above;
  }
  __syncthreads();
  int T = s_T; u32 above = s_above;

  // collect pass (float4 reads)
  for(int i=tid;i<NN/4;i+=256){
    float4 vv = srow4[i];
    float va[4] = {vv.x, vv.y, vv.z, vv.w};
    #pragma unroll
    for(int cix=0;cix<4;cix++){
      float v = va[cix];
      int k = (int)(fkey(v)>>20);
      if(k > T){
        u32 p = atomicAdd(&s_na,1u);
        if(p < (u32)KC){ int n = i*4+cix; cidx_out[b*KC+p] = n; metc[b*KC+p] = v; }
      } else if(k == T){
        u32 p = atomicAdd(&s_nc,1u);
        if(p < CAP){ cval[p]=v; cidxs[p]=i*4+cix; }
      }
    }
  }
  __syncthreads();
  int need = KC - (int)above; if(need < 0) need = 0;
  int Mc = (int)s_nc; if(Mc > CAP) Mc = CAP;

  // ---- refine: sub-histogram over key bits 8..19 of the Mc tie items ----
  for(int e=tid;e<4096;e+=256) hist[e]=0;
  __syncthreads();
  for(int e=tid;e<Mc;e+=256) atomicAdd(&hist[(fkey(cval[e])>>8)&0xFFFu], 1u);
  __syncthreads();
  u32 c2=0;
  #pragma unroll
  for(int i=0;i<16;i++) c2 += hist[tid*16+i];
  cs[tid]=c2;
  __syncthreads();
  if(tid==0){
    if(need == 0){ s_T2 = 4096; s_above2 = 0; }
    else {
      u32 acc=0, above2=0; int T2=0;
      for(int ch=255; ch>=0; --ch){
        if(acc + cs[ch] >= (u32)need){
          for(int bin=ch*16+15;; --bin){
            if(acc + hist[bin] >= (u32)need){ T2=bin; above2=acc; break; }
            acc += hist[bin];
          }
          break;
        }
        acc += cs[ch];
      }
      s_T2 = T2; s_above2 = above2;
    }
  }
  __syncthreads();
  int T2 = s_T2; u32 above2 = s_above2;

  // emit tie items with sub > T2 directly (exactly above2 of them)
  for(int e=tid;e<Mc;e+=256){
    float v = cval[e];
    int sub = (int)((fkey(v)>>8)&0xFFFu);
    if(sub > T2){
      u32 p = atomicAdd(&s_nb,1u);
      if(p < (u32)need){
        cidx_out[b*KC+above+p] = cidxs[e];
        metc[b*KC+above+p] = v;
      }
      cval[e] = -3.0e38f;
    }
  }
  __syncthreads();

  // residual serial extraction: need2 = need - above2 items (typically 1-2)
  int need2 = need - (int)above2; if(need2 < 0) need2 = 0;
  for(int r=0;r<need2;r++){
    float v=-3.0e38f; int i=-1;
    for(int e=tid;e<Mc;e+=256){ if(cval[e]>v){v=cval[e];i=e;} }
    int lane=tid&63, w=tid>>6;
    #pragma unroll
    for(int m=32;m>=1;m>>=1){
      float ov=__shfl_xor(v,m,64); int oi=__shfl_xor(i,m,64);
      if(ov>v){v=ov;i=oi;}
    }
    if(lane==0){ swv[w]=v; swi[w]=i; }
    __syncthreads();
    if(tid==0){
      float bv=swv[0]; int bi=swi[0];
      for(int k2=1;k2<4;k2++) if(swv[k2]>bv){bv=swv[k2];bi=swi[k2];}
      if(bi >= 0){
        cidx_out[b*KC+above+above2+r] = cidxs[bi];
        metc[b*KC+above+above2+r] = bv;
        cval[bi] = -3.0e38f;
      }
    }
    __syncthreads();
  }
}

// =============== 2-fallback. fused coarse sim + exact top-80 (small ws) ===============
__global__ __launch_bounds__(256) void k_csel(const float* __restrict__ pc,
    const float* __restrict__ qn, int* __restrict__ cidx_out, float* __restrict__ metc)
{
  __shared__ u32 hist[4096];
  __shared__ u32 cs[256];
  __shared__ float cval[CAP];
  __shared__ int  cidxs[CAP];
  __shared__ float s_qn[64];
  __shared__ int s_T; __shared__ u32 s_above;
  __shared__ u32 s_na, s_nc;
  __shared__ float swv[4]; __shared__ int swi[4];
  int b = blockIdx.x, tid = threadIdx.x;

  for(int e=tid;e<4096;e+=256) hist[e]=0;
  if(tid<64) s_qn[tid] = qn[b*64+tid];
  if(tid==0){ s_na=0; s_nc=0; }
  for(int e=tid;e<KC;e+=256){ cidx_out[b*KC+e]=0; metc[b*KC+e]=-1.0f; }
  __syncthreads();

  for(int n=tid;n<NN;n+=256){
    float v = row_sim(pc + (size_t)n*64, s_qn);
    atomicAdd(&hist[fkey(v)>>20], 1u);
  }
  __syncthreads();
  u32 c=0;
  #pragma unroll
  for(int i=0;i<16;i++) c += hist[tid*16+i];
  cs[tid]=c;
  __syncthreads();
  if(tid==0){
    u32 acc=0, above=0; int T=0;
    for(int ch=255; ch>=0; --ch){
      if(acc + cs[ch] >= (u32)KC){
        for(int bin=ch*16+15;; --bin){
          if(acc + hist[bin] >= (u32)KC){ T=bin; above=acc; break; }
          acc += hist[bin];
        }
        break;
      }
      acc += cs[ch];
    }
    s_T = T; s_above = above;
  }
  __syncthreads();
  int T = s_T; u32 above = s_above;

  for(int n=tid;n<NN;n+=256){
    float v = row_sim(pc + (size_t)n*64, s_qn);
    int k = (int)(fkey(v)>>20);
    if(k > T){
      u32 p = atomicAdd(&s_na,1u);
      if(p < (u32)KC){ cidx_out[b*KC+p] = n; metc[b*KC+p] = v; }
    } else if(k == T){
      u32 p = atomicAdd(&s_nc,1u);
      if(p < CAP){ cval[p]=v; cidxs[p]=n; }
    }
  }
  __syncthreads();
  int need = KC - (int)above; if(need < 0) need = 0;
  int Mc = (int)s_nc; if(Mc > CAP) Mc = CAP;
  for(int r=0;r<need;r++){
    float v=-3.0e38f; int i=-1;
    for(int e=tid;e<Mc;e+=256){ if(cval[e]>v){v=cval[e];i=e;} }
    int lane=tid&63, w=tid>>6;
    #pragma unroll
    for(int m=32;m>=1;m>>=1){
      float ov=__shfl_xor(v,m,64); int oi=__shfl_xor(i,m,64);
      if(ov>v){v=ov;i=oi;}
    }
    if(lane==0){ swv[w]=v; swi[w]=i; }
    __syncthreads();
    if(tid==0){
      float bv=swv[0]; int bi=swi[0];
      for(int k2=1;k2<4;k2++) if(swv[k2]>bv){bv=swv[k2];bi=swi[k2];}
      if(bi >= 0){
        cidx_out[b*KC+above+r] = cidxs[bi];
        metc[b*KC+above+r] = bv;
        cval[bi] = -3.0e38f;
      }
    }
    __syncthreads();
  }
}

// =============== 3. fine series sim + combined score ===============
__global__ __launch_bounds__(256) void k_fine(const float* __restrict__ px,
    const float* __restrict__ x, const int* __restrict__ cidx,
    const float* __restrict__ metc, const float* __restrict__ xn,
    float* __restrict__ comb)
{
  __shared__ float s_red[8];
  int blk = blockIdx.x;
  int b = blk / KC, k = blk % KC;
  int idx = cidx[b*KC+k];
  if(idx < 0) idx = 0;
  if(idx >= NN) idx = NN-1;   // clamp: never OOB
  const float4* pr = (const float4*)(px + (size_t)idx*LC);
  const float4* xr = (const float4*)(x + (size_t)b*LC);
  int tid = threadIdx.x;
  float dot=0.f, ns=0.f;
  for(int i=tid; i<LC/4; i+=256){   // 1344 float4 per row
    float4 a = pr[i], cx = xr[i];
    dot += cx.x*a.x + cx.y*a.y + cx.z*a.z + cx.w*a.w;
    ns  += a.x*a.x + a.y*a.y + a.z*a.z + a.w*a.w;
  }
  dot = wred(dot); ns = wred(ns);
  int lane=tid&63, w=tid>>6;
  if(lane==0){ s_red[w]=dot; s_red[4+w]=ns; }
  __syncthreads();
  if(tid==0){
    float dd = s_red[0]+s_red[1]+s_red[2]+s_red[3];
    float nn = s_red[4]+s_red[5]+s_red[6]+s_red[7];
    float s = dd / ((xn[b]+1e-12f)*(sqrtf(nn)+1e-12f));
    comb[b*KC+k] = 0.7f*metc[b*KC+k] + (1.0f-0.7f)*s;
  }
}

// =============== 4. top-20 + gate MLP + softmax + weighted output (fused) ===============
__global__ __launch_bounds__(256) void k_gateout(const float* __restrict__ comb,
    const float* __restrict__ metc, const int* __restrict__ cidx,
    const float* __restrict__ q, const float* __restrict__ pc,
    const float* __restrict__ gw1, const float* __restrict__ gb1,
    const float* __restrict__ gw2, const float* __restrict__ gb2,
    const float* __restrict__ py, float* __restrict__ out)
{
  __shared__ float s_w1[130*128];
  __shared__ float s_comb[80], s_met[80]; __shared__ int s_ci[80];
  __shared__ float s_q[64];
  __shared__ float s_ctxw[4*64];
  __shared__ float selv[20], selm[20]; __shared__ int seli[20];
  __shared__ float s_gate[20];
  __shared__ float s_wf[20];
  __shared__ float swv2[4]; __shared__ int swi2[4];
  int b=blockIdx.x, tid=threadIdx.x;

  // stage gate W1 cooperatively with float4 (130*128 = 16640 f32 = 4160 f4)
  const float4* g4 = (const float4*)gw1;
  float4* s4 = (float4*)s_w1;
  for(int e=tid;e<4160;e+=256) s4[e] = g4[e];
  if(tid<80){
    s_comb[tid]=comb[b*KC+tid]; s_met[tid]=metc[b*KC+tid];
    int ci = cidx[b*KC+tid];
    if(ci<0) ci=0;
    if(ci>=NN) ci=NN-1;            // clamp: never OOB
    s_ci[tid]=ci;
  }
  if(tid<64) s_q[tid]=q[b*64+tid];
  __syncthreads();

  // exact top-20 by combined score
  for(int r=0;r<TM;r++){
    float v=-3.0e38f; int i=-1;
    if(tid<80){ v=s_comb[tid]; i=tid; }
    int lane=tid&63, w=tid>>6;
    #pragma unroll
    for(int m=32;m>=1;m>>=1){
      float ov=__shfl_xor(v,m,64); int oi=__shfl_xor(i,m,64);
      if(ov>v){v=ov;i=oi;}
    }
    if(lane==0){ swv2[w]=v; swi2[w]=i; }
    __syncthreads();
    if(tid==0){
      float bv=swv2[0]; int bi=swi2[0];
      for(int k2=1;k2<4;k2++) if(swv2[k2]>bv){bv=swv2[k2];bi=swi2[k2];}
      if(bi<0) bi=0;
      selv[r]=bv; selm[r]=s_met[bi]; seli[r]=s_ci[bi];
      s_comb[bi]=-3.0e38f;
    }
    __syncthreads();
  }

  // gate MLP, wave-parallel over m: each wave computes both hidden halves.
  int w = tid>>6, ln = tid&63;
  for(int m=w; m<TM; m+=4){
    s_ctxw[w*64+ln] = pc[(size_t)seli[m]*64 + ln];   // wave-local stage
    float a  = gb1[ln];
    float a2 = gb1[64+ln];
    for(int i=0;i<64;i++){
      float qi = s_q[i];
      a  += qi*s_w1[i*128+ln];
      a2 += qi*s_w1[i*128+64+ln];
    }
    for(int i=0;i<64;i++){
      float ci = s_ctxw[w*64+i];
      a  += ci*s_w1[(64+i)*128+ln];
      a2 += ci*s_w1[(64+i)*128+64+ln];
    }
    a  += selv[m]*s_w1[128*128+ln];
    a  += selm[m]*s_w1[129*128+ln];
    a2 += selv[m]*s_w1[128*128+64+ln];
    a2 += selm[m]*s_w1[129*128+64+ln];
    float h = gelu(a)*gw2[ln] + gelu(a2)*gw2[64+ln];
    float s = wred(h);
    if(ln==0) s_gate[m] = s + gb2[0];
  }
  __syncthreads();

  if(tid==0){
    float lg[20]; float mx=-3.0e38f;
    for(int m=0;m<TM;m++){ lg[m] = selv[m]*10.0f + s_gate[m]; if(lg[m]>mx) mx=lg[m]; }
    float ss=0.f;
    for(int m=0;m<TM;m++){ lg[m]=expf(lg[m]-mx); ss+=lg[m]; }
    for(int m=0;m<TM;m++) s_wf[m]=lg[m]/ss;
  }
  __syncthreads();

  // weighted sum of pool_y rows -> output (same per-element m-order as before)
  const float4* py4 = (const float4*)py;
  for(int e4=tid; e4<PP*CC/4; e4+=256){   // 384 float4 per row
    float4 acc = make_float4(0.f,0.f,0.f,0.f);
    #pragma unroll
    for(int m=0;m<TM;m++){
      float4 v = py4[(size_t)seli[m]*(PP*CC/4) + e4];
      float wm = s_wf[m];
      acc.x += wm*v.x; acc.y += wm*v.y; acc.z += wm*v.z; acc.w += wm*v.w;
    }
    ((float4*)out)[(size_t)b*(PP*CC/4) + e4] = acc;
  }
}

extern "C" void kernel_launch(void* const* d_in, const int* in_sizes, int n_in,
                              void* d_out, int out_size, void* d_ws, size_t ws_size,
                              hipStream_t stream) {
  const int*   mids = (const int*)d_in[0];
  const float* exo  = (const float*)d_in[1];
  const float* locs = (const float*)d_in[2];
  const float* x    = (const float*)d_in[3];
  const float* pc   = (const float*)d_in[4];
  const float* px   = (const float*)d_in[5];
  const float* py   = (const float*)d_in[6];
  const float* emb  = (const float*)d_in[7];
  const float* cw1  = (const float*)d_in[8];
  const float* cb1  = (const float*)d_in[9];
  const float* cw2  = (const float*)d_in[10];
  const float* cb2  = (const float*)d_in[11];
  const float* ew1  = (const float*)d_in[12];
  const float* eb1  = (const float*)d_in[13];
  const float* ew2  = (const float*)d_in[14];
  const float* eb2  = (const float*)d_in[15];
  const float* lw1  = (const float*)d_in[16];
  const float* lb1  = (const float*)d_in[17];
  const float* lw2  = (const float*)d_in[18];
  const float* lb2  = (const float*)d_in[19];
  const float* lng  = (const float*)d_in[20];
  const float* lnb  = (const float*)d_in[21];
  const float* gw1  = (const float*)d_in[22];
  const float* gb1  = (const float*)d_in[23];
  const float* gw2  = (const float*)d_in[24];
  const float* gb2  = (const float*)d_in[25];
  float* out = (float*)d_out;

  char* ws = (char*)d_ws;
  float* q    = (float*)(ws + OFF_Q);
  float* qn   = (float*)(ws + OFF_QN);
  float* xn   = (float*)(ws + OFF_XN);
  int*   cidx = (int*)  (ws + OFF_CIDX);
  float* metc = (float*)(ws + OFF_METC);
  float* comb = (float*)(ws + OFF_COMB);
  float* sims = (float*)(ws + OFF_SIM);
  u32*   ghist= (u32*)  (ws + OFF_HIST);

  bool big = (ws_size >= (size_t)WS_NEED);

  k_ctx<<<BB, 64, 0, stream>>>(mids, exo, locs, x, emb,
      cw1, cb1, cw2, cb2, ew1, eb1, ew2, eb2,
      lw1, lb1, lw2, lb2, lng, lnb, q, qn, xn,
      big ? ghist : (u32*)nullptr);

  if(big){
    // single-pass sim + fused histogram, then light selection
    k_sim<<<(NN+63)/64, 256, 0, stream>>>(pc, qn, sims, ghist);
    k_sel<<<BB, 256, 0, stream>>>(sims, ghist, cidx, metc);
  } else {
    // fallback: fused low-parallelism version (ws too small)
    k_csel<<<BB, 256, 0, stream>>>(pc, qn, cidx, metc);
  }

  k_fine<<<BB*KC, 256, 0, stream>>>(px, x, cidx, metc, xn, comb);
  k_gateout<<<BB, 256, 0, stream>>>(comb, metc, cidx, q, pc,
      gw1, gb1, gw2, gb2, py, out);
}

// Round 6
// 751.240 us; speedup vs baseline: 1.1979x; 1.1979x over previous
//
#include <hip/hip_runtime.h>
#include <math.h>

typedef unsigned int u32;

#define BB 64
#define NN 20000
#define LL 336
#define PP 96
#define CC 16
#define DD 64
#define KC 80
#define TM 20
#define LC 5376     // L*C
#define NTAB 17
#define GH 128
#define CAP 2048    // threshold-bin candidate buffer

__constant__ int c_idmin[17] = {0,0,0,0,0,1,1,0,0,0,0,0,0,0,0,0,0};
__constant__ int c_idmax[17] = {2047,255,4095,23,6,12,53,3,1,1,15,7,2,2,2,2,1};

__device__ __forceinline__ float gelu(float x){ return 0.5f*x*(1.0f + erff(x*0.70710678118654752440f)); }
__device__ __forceinline__ float wred(float v){
  #pragma unroll
  for(int m=32;m>=1;m>>=1) v += __shfl_xor(v, m, 64);
  return v;
}
__device__ __forceinline__ u32 fkey(float f){
  u32 u = __float_as_uint(f);
  return (u & 0x80000000u) ? ~u : (u | 0x80000000u);
}

// ---------------- workspace layout (bytes) ----------------
#define OFF_Q     0u            // 4096 f32
#define OFF_QN    16384u        // 4096 f32
#define OFF_XN    32768u        // 64 f32
#define OFF_CIDX  33024u        // 64*80 i32
#define OFF_METC  53504u        // 64*80 f32
#define OFF_COMB  73984u        // 64*80 f32
#define OFF_SIM   106496u       // 64*20000 f32 = 5,120,000 B (needs ~5.3 MB ws)

// =============== 1. context encoder -> q, qn, xnorm ===============
__global__ __launch_bounds__(64) void k_ctx(
    const int* __restrict__ mids, const float* __restrict__ exo,
    const float* __restrict__ locs, const float* __restrict__ x,
    const float* __restrict__ emb,
    const float* __restrict__ cw1, const float* __restrict__ cb1,
    const float* __restrict__ cw2, const float* __restrict__ cb2,
    const float* __restrict__ ew1, const float* __restrict__ eb1,
    const float* __restrict__ ew2, const float* __restrict__ eb2,
    const float* __restrict__ lw1, const float* __restrict__ lb1,
    const float* __restrict__ lw2, const float* __restrict__ lb2,
    const float* __restrict__ lng, const float* __restrict__ lnb,
    float* __restrict__ q, float* __restrict__ qn, float* __restrict__ xn)
{
  int b = blockIdx.x, j = threadIdx.x;
  __shared__ float s_cat[272];
  __shared__ float s_h[64];
  __shared__ float s_exo[8];
  __shared__ float s_loc[12];

  for(int e=j; e<272; e+=64){
    int t=e>>4, c=e&15;
    int id = mids[b*NTAB + t];
    if(id < c_idmin[t]) id = c_idmin[t];
    if(id > c_idmax[t]) id = c_idmax[t];
    s_cat[e] = emb[((size_t)t*4096 + id)*16 + c];
  }
  if(j<8)  s_exo[j] = exo[b*8+j];
  if(j<12) s_loc[j] = locs[b*12+j];
  __syncthreads();

  // cat MLP: 272 -> 64 (gelu) -> 64
  float a = cb1[j];
  for(int i=0;i<272;i++) a += s_cat[i]*cw1[i*64+j];
  s_h[j] = gelu(a);
  __syncthreads();
  float cc = cb2[j];
  for(int k=0;k<64;k++) cc += s_h[k]*cw2[k*64+j];
  __syncthreads();

  // exo MLP: 8 -> 64 (gelu) -> 64
  a = eb1[j];
  for(int i=0;i<8;i++) a += s_exo[i]*ew1[i*64+j];
  s_h[j] = gelu(a);
  __syncthreads();
  float ec = eb2[j];
  for(int k=0;k<64;k++) ec += s_h[k]*ew2[k*64+j];
  cc += ec;
  __syncthreads();

  // loc MLP per period r: 4 -> 64 (gelu) -> 64
  float lr[3];
  for(int r=0;r<3;r++){
    a = lb1[j];
    for(int i=0;i<4;i++) a += s_loc[r*4+i]*lw1[i*64+j];
    s_h[j] = gelu(a);
    __syncthreads();
    float o = lb2[j];
    for(int k=0;k<64;k++) o += s_h[k]*lw2[k*64+j];
    lr[r] = o;
    __syncthreads();
  }

  // LayerNorm per period + mean over periods
  float g = lng[j], be = lnb[j];
  float qa = 0.f;
  for(int r=0;r<3;r++){
    float v = cc + lr[r];
    float mean = wred(v) * (1.0f/64.0f);
    float d = v - mean;
    float var = wred(d*d) * (1.0f/64.0f);
    qa += d / sqrtf(var + 1e-5f) * g + be;
  }
  float qv = qa * (1.0f/3.0f);
  q[b*64+j] = qv;
  float s2 = wred(qv*qv);
  qn[b*64+j] = qv / (sqrtf(s2) + 1e-12f);

  // ||x[b]|| over 5376 elements
  float xa = 0.f;
  for(int e=j; e<LC; e+=64){ float f = x[(size_t)b*LC+e]; xa += f*f; }
  xa = wred(xa);
  if(j==0) xn[b] = sqrtf(xa);
}

// shared sim routine (fallback path): noinline so both passes emit the SAME
// code instance -> bitwise-identical values in histogram and collect passes.
__device__ __attribute__((noinline)) float row_sim(const float* pr, const float* sq)
{
  const float4* p4 = (const float4*)pr;
  float dot=0.f, ns=0.f;
  #pragma unroll
  for(int i=0;i<16;i++){
    float4 u = p4[i];
    dot += u.x*sq[i*4+0] + u.y*sq[i*4+1] + u.z*sq[i*4+2] + u.w*sq[i*4+3];
    ns  += u.x*u.x + u.y*u.y + u.z*u.z + u.w*u.w;
  }
  return dot / (sqrtf(ns) + 1e-12f);
}

// =============== 2a. coarse sims, massively parallel ===============
// grid (ceil(N/64), B/4) = (313,16) = 5008 blocks; each block: 64 pool rows x 4 batch rows.
// Accumulation order per (b,n) is identical to row_sim (sequential float4 chain),
// so selection semantics match the fallback path bit-for-bit.
// (Round-5 lesson: this layout, NOT the all-64-b + ballot-histogram variant --
//  the wave-dedup loop serialized ~30 cross-lane iterations per wave per b
//  and cost +145 us. Reverted to this verified-755us structure.)
__global__ __launch_bounds__(256) void k_sim(const float* __restrict__ pc,
    const float* __restrict__ qn, float* __restrict__ sim)
{
  __shared__ float s_pc[64*68];   // row stride 68 f32 (272 B, 16B-aligned; b128 reads conflict-free)
  __shared__ float s_qn[4*64];
  int n0 = blockIdx.x << 6;
  int b0 = blockIdx.y << 2;
  int tid = threadIdx.x;

  // stage 64 pool_context rows, coalesced float4
  const float4* pc4 = (const float4*)pc;
  for(int e=tid; e<64*16; e+=256){
    int r = e>>4, c = e&15;
    float4 v;
    if(n0 + r < NN) v = pc4[(size_t)(n0+r)*16 + c];
    else            v = make_float4(0.f,0.f,0.f,0.f);
    *(float4*)&s_pc[r*68 + c*4] = v;
  }
  s_qn[tid] = qn[(size_t)(b0 + (tid>>6))*64 + (tid&63)];
  __syncthreads();

  int bl = tid>>6, ln = tid&63;   // wave = one b, lane = one n
  const float4* q4 = (const float4*)&s_qn[bl*64];   // broadcast reads
  const float4* p4 = (const float4*)&s_pc[ln*68];   // per-lane, conflict-free
  float dot=0.f, ns=0.f;
  #pragma unroll
  for(int i=0;i<16;i++){
    float4 p = p4[i], qv = q4[i];
    dot += p.x*qv.x + p.y*qv.y + p.z*qv.z + p.w*qv.w;
    ns  += p.x*p.x + p.y*p.y + p.z*p.z + p.w*p.w;
  }
  int n = n0 + ln;
  if(n < NN) sim[(size_t)(b0+bl)*NN + n] = dot / (sqrtf(ns) + 1e-12f);
}

// =============== 2b. exact top-80 per batch row from precomputed sims ===============
// Hierarchical radix select: 12-bit key histogram -> threshold bin T; then a
// SECOND 12-bit histogram (key bits 8..19) over only the tie items (already in
// LDS) -> sub-threshold T2. Items with sub>T2 are emitted directly; only the
// residual ties at (T,T2) -- items sharing 24 leading key bits, typically 1-2 --
// go through the serial max-extraction loop. Selected SET identical to before.
__global__ __launch_bounds__(256) void k_sel(const float* __restrict__ sim,
    int* __restrict__ cidx_out, float* __restrict__ metc)
{
  __shared__ u32 hist[4096];
  __shared__ u32 cs[256];
  __shared__ float cval[CAP];
  __shared__ int  cidxs[CAP];
  __shared__ int s_T; __shared__ u32 s_above;
  __shared__ int s_T2; __shared__ u32 s_above2;
  __shared__ u32 s_na, s_nc, s_nb;
  __shared__ float swv[4]; __shared__ int swi[4];
  int b = blockIdx.x, tid = threadIdx.x;
  const float* srow = sim + (size_t)b*NN;
  const float4* srow4 = (const float4*)srow;   // NN = 20000 = 5000 float4

  for(int e=tid;e<4096;e+=256) hist[e]=0;
  if(tid==0){ s_na=0; s_nc=0; s_nb=0; }
  // defensive prefill: any slot a later pass fails to write stays a VALID index
  for(int e=tid;e<KC;e+=256){ cidx_out[b*KC+e]=0; metc[b*KC+e]=-1.0f; }
  __syncthreads();

  // pass A: histogram of similarity keys (float4 reads; order-agnostic)
  for(int i=tid;i<NN/4;i+=256){
    float4 v = srow4[i];
    atomicAdd(&hist[fkey(v.x)>>20], 1u);
    atomicAdd(&hist[fkey(v.y)>>20], 1u);
    atomicAdd(&hist[fkey(v.z)>>20], 1u);
    atomicAdd(&hist[fkey(v.w)>>20], 1u);
  }
  __syncthreads();
  u32 c=0;
  #pragma unroll
  for(int i=0;i<16;i++) c += hist[tid*16+i];
  cs[tid]=c;
  __syncthreads();
  if(tid==0){
    u32 acc=0, above=0; int T=0;
    for(int ch=255; ch>=0; --ch){
      if(acc + cs[ch] >= (u32)KC){
        for(int bin=ch*16+15;; --bin){
          if(acc + hist[bin] >= (u32)KC){ T=bin; above=acc; break; }
          acc += hist[bin];
        }
        break;
      }
      acc += cs[ch];
    }
    s_T = T; s_above = above;
  }
  __syncthreads();
  int T = s_T; u32 above = s_above;

  // pass B: collect (float4 reads)
  for(int i=tid;i<NN/4;i+=256){
    float4 vv = srow4[i];
    float va[4] = {vv.x, vv.y, vv.z, vv.w};
    #pragma unroll
    for(int cix=0;cix<4;cix++){
      float v = va[cix];
      int k = (int)(fkey(v)>>20);
      if(k > T){
        u32 p = atomicAdd(&s_na,1u);
        if(p < (u32)KC){ int n = i*4+cix; cidx_out[b*KC+p] = n; metc[b*KC+p] = v; }
      } else if(k == T){
        u32 p = atomicAdd(&s_nc,1u);
        if(p < CAP){ cval[p]=v; cidxs[p]=i*4+cix; }
      }
    }
  }
  __syncthreads();
  int need = KC - (int)above; if(need < 0) need = 0;
  int Mc = (int)s_nc; if(Mc > CAP) Mc = CAP;

  // ---- refine: sub-histogram over key bits 8..19 of the Mc tie items ----
  for(int e=tid;e<4096;e+=256) hist[e]=0;
  __syncthreads();
  for(int e=tid;e<Mc;e+=256) atomicAdd(&hist[(fkey(cval[e])>>8)&0xFFFu], 1u);
  __syncthreads();
  u32 c2=0;
  #pragma unroll
  for(int i=0;i<16;i++) c2 += hist[tid*16+i];
  cs[tid]=c2;
  __syncthreads();
  if(tid==0){
    if(need == 0){ s_T2 = 4096; s_above2 = 0; }
    else {
      u32 acc=0, above2=0; int T2=0;
      for(int ch=255; ch>=0; --ch){
        if(acc + cs[ch] >= (u32)need){
          for(int bin=ch*16+15;; --bin){
            if(acc + hist[bin] >= (u32)need){ T2=bin; above2=acc; break; }
            acc += hist[bin];
          }
          break;
        }
        acc += cs[ch];
      }
      s_T2 = T2; s_above2 = above2;
    }
  }
  __syncthreads();
  int T2 = s_T2; u32 above2 = s_above2;

  // emit tie items with sub > T2 directly (exactly above2 of them; within-class
  // slot order is atomic-arbitrary, same as the k>T class -- order-agnostic downstream)
  for(int e=tid;e<Mc;e+=256){
    float v = cval[e];
    int sub = (int)((fkey(v)>>8)&0xFFFu);
    if(sub > T2){
      u32 p = atomicAdd(&s_nb,1u);
      if(p < (u32)need){
        cidx_out[b*KC+above+p] = cidxs[e];
        metc[b*KC+above+p] = v;
      }
      cval[e] = -3.0e38f;   // remove from residual pool (each e touched by exactly one thread)
    }
  }
  __syncthreads();

  // residual serial extraction: need2 = need - above2 items (typically 1-2)
  int need2 = need - (int)above2; if(need2 < 0) need2 = 0;
  for(int r=0;r<need2;r++){
    float v=-3.0e38f; int i=-1;
    for(int e=tid;e<Mc;e+=256){ if(cval[e]>v){v=cval[e];i=e;} }
    int lane=tid&63, w=tid>>6;
    #pragma unroll
    for(int m=32;m>=1;m>>=1){
      float ov=__shfl_xor(v,m,64); int oi=__shfl_xor(i,m,64);
      if(ov>v){v=ov;i=oi;}
    }
    if(lane==0){ swv[w]=v; swi[w]=i; }
    __syncthreads();
    if(tid==0){
      float bv=swv[0]; int bi=swi[0];
      for(int k2=1;k2<4;k2++) if(swv[k2]>bv){bv=swv[k2];bi=swi[k2];}
      if(bi >= 0){
        cidx_out[b*KC+above+above2+r] = cidxs[bi];
        metc[b*KC+above+above2+r] = bv;
        cval[bi] = -3.0e38f;
      }
    }
    __syncthreads();
  }
}

// =============== 2-fallback. fused coarse sim + exact top-80 (small ws) ===============
__global__ __launch_bounds__(256) void k_csel(const float* __restrict__ pc,
    const float* __restrict__ qn, int* __restrict__ cidx_out, float* __restrict__ metc)
{
  __shared__ u32 hist[4096];
  __shared__ u32 cs[256];
  __shared__ float cval[CAP];
  __shared__ int  cidxs[CAP];
  __shared__ float s_qn[64];
  __shared__ int s_T; __shared__ u32 s_above;
  __shared__ u32 s_na, s_nc;
  __shared__ float swv[4]; __shared__ int swi[4];
  int b = blockIdx.x, tid = threadIdx.x;

  for(int e=tid;e<4096;e+=256) hist[e]=0;
  if(tid<64) s_qn[tid] = qn[b*64+tid];
  if(tid==0){ s_na=0; s_nc=0; }
  for(int e=tid;e<KC;e+=256){ cidx_out[b*KC+e]=0; metc[b*KC+e]=-1.0f; }
  __syncthreads();

  for(int n=tid;n<NN;n+=256){
    float v = row_sim(pc + (size_t)n*64, s_qn);
    atomicAdd(&hist[fkey(v)>>20], 1u);
  }
  __syncthreads();
  u32 c=0;
  #pragma unroll
  for(int i=0;i<16;i++) c += hist[tid*16+i];
  cs[tid]=c;
  __syncthreads();
  if(tid==0){
    u32 acc=0, above=0; int T=0;
    for(int ch=255; ch>=0; --ch){
      if(acc + cs[ch] >= (u32)KC){
        for(int bin=ch*16+15;; --bin){
          if(acc + hist[bin] >= (u32)KC){ T=bin; above=acc; break; }
          acc += hist[bin];
        }
        break;
      }
      acc += cs[ch];
    }
    s_T = T; s_above = above;
  }
  __syncthreads();
  int T = s_T; u32 above = s_above;

  for(int n=tid;n<NN;n+=256){
    float v = row_sim(pc + (size_t)n*64, s_qn);
    int k = (int)(fkey(v)>>20);
    if(k > T){
      u32 p = atomicAdd(&s_na,1u);
      if(p < (u32)KC){ cidx_out[b*KC+p] = n; metc[b*KC+p] = v; }
    } else if(k == T){
      u32 p = atomicAdd(&s_nc,1u);
      if(p < CAP){ cval[p]=v; cidxs[p]=n; }
    }
  }
  __syncthreads();
  int need = KC - (int)above; if(need < 0) need = 0;
  int Mc = (int)s_nc; if(Mc > CAP) Mc = CAP;
  for(int r=0;r<need;r++){
    float v=-3.0e38f; int i=-1;
    for(int e=tid;e<Mc;e+=256){ if(cval[e]>v){v=cval[e];i=e;} }
    int lane=tid&63, w=tid>>6;
    #pragma unroll
    for(int m=32;m>=1;m>>=1){
      float ov=__shfl_xor(v,m,64); int oi=__shfl_xor(i,m,64);
      if(ov>v){v=ov;i=oi;}
    }
    if(lane==0){ swv[w]=v; swi[w]=i; }
    __syncthreads();
    if(tid==0){
      float bv=swv[0]; int bi=swi[0];
      for(int k2=1;k2<4;k2++) if(swv[k2]>bv){bv=swv[k2];bi=swi[k2];}
      if(bi >= 0){
        cidx_out[b*KC+above+r] = cidxs[bi];
        metc[b*KC+above+r] = bv;
        cval[bi] = -3.0e38f;
      }
    }
    __syncthreads();
  }
}

// =============== 3. fine series sim + combined score ===============
__global__ __launch_bounds__(256) void k_fine(const float* __restrict__ px,
    const float* __restrict__ x, const int* __restrict__ cidx,
    const float* __restrict__ metc, const float* __restrict__ xn,
    float* __restrict__ comb)
{
  __shared__ float s_red[8];
  int blk = blockIdx.x;
  int b = blk / KC, k = blk % KC;
  int idx = cidx[b*KC+k];
  if(idx < 0) idx = 0;
  if(idx >= NN) idx = NN-1;   // clamp: never OOB
  const float4* pr = (const float4*)(px + (size_t)idx*LC);
  const float4* xr = (const float4*)(x + (size_t)b*LC);
  int tid = threadIdx.x;
  float dot=0.f, ns=0.f;
  for(int i=tid; i<LC/4; i+=256){   // 1344 float4 per row
    float4 a = pr[i], cx = xr[i];
    dot += cx.x*a.x + cx.y*a.y + cx.z*a.z + cx.w*a.w;
    ns  += a.x*a.x + a.y*a.y + a.z*a.z + a.w*a.w;
  }
  dot = wred(dot); ns = wred(ns);
  int lane=tid&63, w=tid>>6;
  if(lane==0){ s_red[w]=dot; s_red[4+w]=ns; }
  __syncthreads();
  if(tid==0){
    float dd = s_red[0]+s_red[1]+s_red[2]+s_red[3];
    float nn = s_red[4]+s_red[5]+s_red[6]+s_red[7];
    float s = dd / ((xn[b]+1e-12f)*(sqrtf(nn)+1e-12f));
    comb[b*KC+k] = 0.7f*metc[b*KC+k] + (1.0f-0.7f)*s;
  }
}

// =============== 4. top-20 + gate MLP + softmax + weighted output (fused) ===============
__global__ __launch_bounds__(256) void k_gateout(const float* __restrict__ comb,
    const float* __restrict__ metc, const int* __restrict__ cidx,
    const float* __restrict__ q, const float* __restrict__ pc,
    const float* __restrict__ gw1, const float* __restrict__ gb1,
    const float* __restrict__ gw2, const float* __restrict__ gb2,
    const float* __restrict__ py, float* __restrict__ out)
{
  __shared__ float s_w1[130*128];
  __shared__ float s_comb[80], s_met[80]; __shared__ int s_ci[80];
  __shared__ float s_q[64];
  __shared__ float s_ctxw[4*64];
  __shared__ float selv[20], selm[20]; __shared__ int seli[20];
  __shared__ float s_gate[20];
  __shared__ float s_wf[20];
  __shared__ float swv2[4]; __shared__ int swi2[4];
  int b=blockIdx.x, tid=threadIdx.x;

  // stage gate W1 cooperatively with float4 (130*128 = 16640 f32 = 4160 f4)
  const float4* g4 = (const float4*)gw1;
  float4* s4 = (float4*)s_w1;
  for(int e=tid;e<4160;e+=256) s4[e] = g4[e];
  if(tid<80){
    s_comb[tid]=comb[b*KC+tid]; s_met[tid]=metc[b*KC+tid];
    int ci = cidx[b*KC+tid];
    if(ci<0) ci=0;
    if(ci>=NN) ci=NN-1;            // clamp: never OOB
    s_ci[tid]=ci;
  }
  if(tid<64) s_q[tid]=q[b*64+tid];
  __syncthreads();

  // exact top-20 by combined score
  for(int r=0;r<TM;r++){
    float v=-3.0e38f; int i=-1;
    if(tid<80){ v=s_comb[tid]; i=tid; }
    int lane=tid&63, w=tid>>6;
    #pragma unroll
    for(int m=32;m>=1;m>>=1){
      float ov=__shfl_xor(v,m,64); int oi=__shfl_xor(i,m,64);
      if(ov>v){v=ov;i=oi;}
    }
    if(lane==0){ swv2[w]=v; swi2[w]=i; }
    __syncthreads();
    if(tid==0){
      float bv=swv2[0]; int bi=swi2[0];
      for(int k2=1;k2<4;k2++) if(swv2[k2]>bv){bv=swv2[k2];bi=swi2[k2];}
      if(bi<0) bi=0;
      selv[r]=bv; selm[r]=s_met[bi]; seli[r]=s_ci[bi];
      s_comb[bi]=-3.0e38f;
    }
    __syncthreads();
  }

  // gate MLP, wave-parallel over m: each wave computes both hidden halves.
  int w = tid>>6, ln = tid&63;
  for(int m=w; m<TM; m+=4){
    s_ctxw[w*64+ln] = pc[(size_t)seli[m]*64 + ln];   // wave-local stage
    float a  = gb1[ln];
    float a2 = gb1[64+ln];
    for(int i=0;i<64;i++){
      float qi = s_q[i];
      a  += qi*s_w1[i*128+ln];
      a2 += qi*s_w1[i*128+64+ln];
    }
    for(int i=0;i<64;i++){
      float ci = s_ctxw[w*64+i];
      a  += ci*s_w1[(64+i)*128+ln];
      a2 += ci*s_w1[(64+i)*128+64+ln];
    }
    a  += selv[m]*s_w1[128*128+ln];
    a  += selm[m]*s_w1[129*128+ln];
    a2 += selv[m]*s_w1[128*128+64+ln];
    a2 += selm[m]*s_w1[129*128+64+ln];
    float h = gelu(a)*gw2[ln] + gelu(a2)*gw2[64+ln];
    float s = wred(h);
    if(ln==0) s_gate[m] = s + gb2[0];
  }
  __syncthreads();

  if(tid==0){
    float lg[20]; float mx=-3.0e38f;
    for(int m=0;m<TM;m++){ lg[m] = selv[m]*10.0f + s_gate[m]; if(lg[m]>mx) mx=lg[m]; }
    float ss=0.f;
    for(int m=0;m<TM;m++){ lg[m]=expf(lg[m]-mx); ss+=lg[m]; }
    for(int m=0;m<TM;m++) s_wf[m]=lg[m]/ss;
  }
  __syncthreads();

  // weighted sum of pool_y rows -> output (same per-element m-order as before)
  const float4* py4 = (const float4*)py;
  for(int e4=tid; e4<PP*CC/4; e4+=256){   // 384 float4 per row
    float4 acc = make_float4(0.f,0.f,0.f,0.f);
    #pragma unroll
    for(int m=0;m<TM;m++){
      float4 v = py4[(size_t)seli[m]*(PP*CC/4) + e4];
      float wm = s_wf[m];
      acc.x += wm*v.x; acc.y += wm*v.y; acc.z += wm*v.z; acc.w += wm*v.w;
    }
    ((float4*)out)[(size_t)b*(PP*CC/4) + e4] = acc;
  }
}

extern "C" void kernel_launch(void* const* d_in, const int* in_sizes, int n_in,
                              void* d_out, int out_size, void* d_ws, size_t ws_size,
                              hipStream_t stream) {
  const int*   mids = (const int*)d_in[0];
  const float* exo  = (const float*)d_in[1];
  const float* locs = (const float*)d_in[2];
  const float* x    = (const float*)d_in[3];
  const float* pc   = (const float*)d_in[4];
  const float* px   = (const float*)d_in[5];
  const float* py   = (const float*)d_in[6];
  const float* emb  = (const float*)d_in[7];
  const float* cw1  = (const float*)d_in[8];
  const float* cb1  = (const float*)d_in[9];
  const float* cw2  = (const float*)d_in[10];
  const float* cb2  = (const float*)d_in[11];
  const float* ew1  = (const float*)d_in[12];
  const float* eb1  = (const float*)d_in[13];
  const float* ew2  = (const float*)d_in[14];
  const float* eb2  = (const float*)d_in[15];
  const float* lw1  = (const float*)d_in[16];
  const float* lb1  = (const float*)d_in[17];
  const float* lw2  = (const float*)d_in[18];
  const float* lb2  = (const float*)d_in[19];
  const float* lng  = (const float*)d_in[20];
  const float* lnb  = (const float*)d_in[21];
  const float* gw1  = (const float*)d_in[22];
  const float* gb1  = (const float*)d_in[23];
  const float* gw2  = (const float*)d_in[24];
  const float* gb2  = (const float*)d_in[25];
  float* out = (float*)d_out;

  char* ws = (char*)d_ws;
  float* q    = (float*)(ws + OFF_Q);
  float* qn   = (float*)(ws + OFF_QN);
  float* xn   = (float*)(ws + OFF_XN);
  int*   cidx = (int*)  (ws + OFF_CIDX);
  float* metc = (float*)(ws + OFF_METC);
  float* comb = (float*)(ws + OFF_COMB);
  float* sims = (float*)(ws + OFF_SIM);

  k_ctx<<<BB, 64, 0, stream>>>(mids, exo, locs, x, emb,
      cw1, cb1, cw2, cb2, ew1, eb1, ew2, eb2,
      lw1, lb1, lw2, lb2, lng, lnb, q, qn, xn);

  size_t need_sim = (size_t)OFF_SIM + (size_t)BB*NN*sizeof(float);
  if(ws_size >= need_sim){
    // parallel path: 5008-block sim GEMV + light per-row selection
    k_sim<<<dim3((NN+63)/64, BB/4), 256, 0, stream>>>(pc, qn, sims);
    k_sel<<<BB, 256, 0, stream>>>(sims, cidx, metc);
  } else {
    // fallback: fused low-parallelism version (ws too small)
    k_csel<<<BB, 256, 0, stream>>>(pc, qn, cidx, metc);
  }

  k_fine<<<BB*KC, 256, 0, stream>>>(px, x, cidx, metc, xn, comb);
  k_gateout<<<BB, 256, 0, stream>>>(comb, metc, cidx, q, pc,
      gw1, gb1, gw2, gb2, py, out);
}